// Round 5
// baseline (135.031 us; speedup 1.0000x reference)
//
#include <hip/hip_runtime.h>
#include <hip/hip_bf16.h>

// Problem constants
#define B_  8
#define TQ_ 128
#define TK_ 512
#define D_  256
#define H_  256

#define KSCALE 2.8853900817779268f   // 2*log2(e): exp(2x) = exp2(KSCALE*x)

__device__ __forceinline__ float fast_exp2(float x) {
    return __builtin_amdgcn_exp2f(x);   // v_exp_f32: 2^x
}

__device__ __forceinline__ float wave_red_min(float v) {
#pragma unroll
    for (int o = 32; o > 0; o >>= 1) v = fminf(v, __shfl_xor(v, o));
    return v;
}
__device__ __forceinline__ float wave_red_sum(float v) {
#pragma unroll
    for (int o = 32; o > 0; o >>= 1) v += __shfl_xor(v, o);
    return v;
}

// ---------------------------------------------------------------------------
// Kernel 1: projections, outputs pre-scaled by KSCALE. 8-row tiles.
//   blocks [0,128):   qp[b][q][h]  = KSCALE * sum_d queries[b][q][d]*Wq[d][h]
//   blocks [128,640): kpT[b][h][k] = KSCALE * sum_d keys[b][k][d]*Wk[d][h] (transposed)
// 512 threads: h = t&255, row-half = t>>8 (4 rows each). 2-deep W prefetch.
// ---------------------------------------------------------------------------
__global__ __launch_bounds__(512) void proj_kernel(
    const float* __restrict__ queries, const float* __restrict__ keys,
    const float* __restrict__ Wq, const float* __restrict__ Wk,
    float* __restrict__ qp, float* __restrict__ kpT)
{
    __shared__ __align__(16) float xs[8 * 256];
    __shared__ float tile[8 * 258];    // padded for conflict-free transpose

    const int t  = threadIdx.x;
    const int h  = t & 255;
    const int rh = t >> 8;             // 0/1: rows 0-3 / 4-7
    const bool isQ = (blockIdx.x < 128);
    const float* X; const float* W; int b, r0;
    if (isQ) {
        b = blockIdx.x >> 4; r0 = (blockIdx.x & 15) * 8;
        X = queries + ((size_t)b * TQ_ + r0) * D_;  W = Wq;
    } else {
        int id = blockIdx.x - 128;
        b = id >> 6; r0 = (id & 63) * 8;
        X = keys + ((size_t)b * TK_ + r0) * D_;     W = Wk;
    }

    // stage 8 x 256 input tile (coalesced, 4 elems/thread)
#pragma unroll
    for (int i = 0; i < 4; ++i) {
        int e = i * 512 + t;
        xs[e] = X[e];
    }
    __syncthreads();

    const float* Wcol = W + h;
    // 2-deep rotating prefetch of W columns
    float w0[4], w1[4], w2[4];
#pragma unroll
    for (int j = 0; j < 4; ++j) w0[j] = Wcol[(size_t)j * H_];
#pragma unroll
    for (int j = 0; j < 4; ++j) w1[j] = Wcol[(size_t)(4 + j) * H_];

    float acc[4];
#pragma unroll
    for (int r = 0; r < 4; ++r) acc[r] = 0.0f;
    const int r0l = rh * 4;

    for (int d = 0; d < D_; d += 4) {
        const int dn = (d + 8) & (D_ - 1);   // wraps harmlessly on last 2 iters
#pragma unroll
        for (int j = 0; j < 4; ++j) w2[j] = Wcol[(size_t)(dn + j) * H_];
#pragma unroll
        for (int r = 0; r < 4; ++r) {
            const float4 x4 = *reinterpret_cast<const float4*>(&xs[(r0l + r) * 256 + d]);
            acc[r] = fmaf(x4.x, w0[0], acc[r]);
            acc[r] = fmaf(x4.y, w0[1], acc[r]);
            acc[r] = fmaf(x4.z, w0[2], acc[r]);
            acc[r] = fmaf(x4.w, w0[3], acc[r]);
        }
#pragma unroll
        for (int j = 0; j < 4; ++j) { w0[j] = w1[j]; w1[j] = w2[j]; }
    }
#pragma unroll
    for (int r = 0; r < 4; ++r) acc[r] *= KSCALE;

    if (isQ) {
        float* dst = qp + ((size_t)b * TQ_ + r0 + r0l) * H_ + h;
#pragma unroll
        for (int r = 0; r < 4; ++r) dst[(size_t)r * H_] = acc[r];
    } else {
        // transpose 8 rows x 256 h through LDS, write kpT coalesced-ish
#pragma unroll
        for (int r = 0; r < 4; ++r) tile[(r0l + r) * 258 + h] = acc[r];
        __syncthreads();
        const int rp = t & 7, h0 = t >> 3;   // h0 in 0..63
        float* dst = kpT + (size_t)b * (H_ * TK_) + r0 + rp;
#pragma unroll
        for (int i = 0; i < 4; ++i) {
            int hr = h0 + i * 64;
            dst[(size_t)hr * TK_] = tile[rp * 258 + hr];
        }
    }
}

// ---------------------------------------------------------------------------
// Kernel 2: fused scores + masked softmax + PV. ONE q-row per block.
// grid (128 q, 8 b) = 1024 blocks, 512 threads -> 4 blocks/CU, 32 waves/CU.
// Score: thread t owns k = t, loops all 256 h: acc = sum_h wv*rcp(1+exp2(q'+k')).
// softmax(score) == softmax over k of exp2(KSCALE*(accmin - acc)).
// PV: d = t&255, half = t>>8 (split-k 2-way).
// ---------------------------------------------------------------------------
__global__ __launch_bounds__(512) void attn_kernel(
    const float* __restrict__ qp, const float* __restrict__ kpT,
    const float* __restrict__ values, const int* __restrict__ valid_lens,
    const float* __restrict__ wv, float* __restrict__ out)
{
    __shared__ __align__(16) float qw[H_];     // q-proj row (pre-scaled)
    __shared__ __align__(16) float wvs[H_];
    __shared__ float pe[TK_];                  // unnormalized probs
    __shared__ float red[8];
    __shared__ float red2[8];
    __shared__ float acch[256];                // PV half-1 partials

    const int t = threadIdx.x;
    const int b = blockIdx.y;
    const int q = blockIdx.x;

    const int len = valid_lens[b];             // issue early (scalar)

    // stage q-row + wv
    const float* qpb = qp + ((size_t)b * TQ_ + q) * H_;
    if (t < 256) qw[t] = qpb[t];
    else         wvs[t - 256] = wv[t - 256];
    __syncthreads();

    // ---- score loop: k = t, all 256 h ----
    const int k = t;
    const float* kcol = kpT + (size_t)b * (H_ * TK_) + k;
    float a = 0.f;
    const float4* qw4 = reinterpret_cast<const float4*>(qw);
    const float4* wv4 = reinterpret_cast<const float4*>(wvs);
#pragma unroll 2
    for (int h4 = 0; h4 < 64; ++h4) {
        float k0 = kcol[(size_t)(h4 * 4 + 0) * TK_];
        float k1 = kcol[(size_t)(h4 * 4 + 1) * TK_];
        float k2 = kcol[(size_t)(h4 * 4 + 2) * TK_];
        float k3 = kcol[(size_t)(h4 * 4 + 3) * TK_];
        const float4 q4 = qw4[h4];
        const float4 w4 = wv4[h4];
        float e0 = fast_exp2(q4.x + k0);
        float e1 = fast_exp2(q4.y + k1);
        float e2 = fast_exp2(q4.z + k2);
        float e3 = fast_exp2(q4.w + k3);
        a = fmaf(w4.x, __builtin_amdgcn_rcpf(1.0f + e0), a);
        a = fmaf(w4.y, __builtin_amdgcn_rcpf(1.0f + e1), a);
        a = fmaf(w4.z, __builtin_amdgcn_rcpf(1.0f + e2), a);
        a = fmaf(w4.w, __builtin_amdgcn_rcpf(1.0f + e3), a);
    }

    // ---- masked softmax over k (min of acc == max of score) ----
    const int lane = t & 63, wid = t >> 6;
    const bool valid = (k < len);
    const float BIG = 3.0e38f;

    float m = wave_red_min(valid ? a : BIG);
    if (lane == 0) red[wid] = m;
    __syncthreads();
    float mrow = fminf(fminf(fminf(red[0], red[1]), fminf(red[2], red[3])),
                       fminf(fminf(red[4], red[5]), fminf(red[6], red[7])));

    float e = valid ? fast_exp2((mrow - a) * KSCALE) : 0.f;
    pe[k] = e;
    float S = wave_red_sum(e);
    if (lane == 0) red2[wid] = S;
    __syncthreads();
    float rs = 1.0f / (((red2[0] + red2[1]) + (red2[2] + red2[3])) +
                       ((red2[4] + red2[5]) + (red2[6] + red2[7])));

    // ---- PV: 2-way split-k ----
    const int d = t & 255;
    const int half = t >> 8;
    float c = 0.f;
    const float* vb = values + (size_t)b * (TK_ * D_) + (size_t)(half * 256) * D_ + d;
    const float* pb = &pe[half * 256];
#pragma unroll 8
    for (int kk = 0; kk < 256; ++kk) {
        c = fmaf(pb[kk], vb[(size_t)kk * D_], c);
    }
    if (half == 1) acch[d] = c;
    __syncthreads();
    if (half == 0) {
        out[((size_t)b * TQ_ + q) * D_ + d] = (c + acch[d]) * rs;
    }
}

extern "C" void kernel_launch(void* const* d_in, const int* in_sizes, int n_in,
                              void* d_out, int out_size, void* d_ws, size_t ws_size,
                              hipStream_t stream) {
    const float* queries    = (const float*)d_in[0];
    const float* keys       = (const float*)d_in[1];
    const float* values     = (const float*)d_in[2];
    const int*   valid_lens = (const int*)  d_in[3];
    const float* Wq         = (const float*)d_in[4];
    const float* Wk         = (const float*)d_in[5];
    const float* wv         = (const float*)d_in[6];
    float* out = (float*)d_out;

    float* qp  = (float*)d_ws;                       // B*Tq*H  = 262144 f32
    float* kpT = qp + (size_t)B_ * TQ_ * H_;         // B*H*Tk  = 1048576 f32

    proj_kernel<<<640, 512, 0, stream>>>(queries, keys, Wq, Wk, qp, kpT);
    attn_kernel<<<dim3(TQ_, B_), 512, 0, stream>>>(qp, kpT, values, valid_lens, wv, out);
}